// Round 2
// baseline (596.831 us; speedup 1.0000x reference)
//
#include <hip/hip_runtime.h>
#include <math.h>

// Problem constants
#define HID   1024
#define NEXP  8
#define CAP   1536
#define NTOK  4096   // B*S = 2*2048

// Output layout (fp32 elements), concatenated flat in reference return order:
//   dispatch [4096,8,1536] | combine [4096,8,1536] | router_probs [4096,8] | aux [1]
#define DISP_OFF 0ull
#define COMB_OFF 50331648ull
#define RP_OFF   100663296ull
#define AUX_OFF  100696064ull

typedef float f32x4 __attribute__((ext_vector_type(4)));

// ---------------- Fused: zero-fill (odd blocks) + GEMM h=relu(x@w1^T+b1) (even blocks) ----
// A [4096,1024] row-major, W [1024(o),1024(h)] row-major (both K-contiguous -> NT GEMM)
#define BM 128
#define BN 128
#define BK 16
#define LDSS (BM + 4)   // 132 floats: float4-aligned row starts (528B), staggered banks

// zero-fill geometry: 2*50331648 floats = 25,165,824 float4 = 256 blocks * 256 thr * 384
#define ZF4_PER_BLOCK 98304
#define ZF4_ITERS     384

__global__ __launch_bounds__(256) void fused_gemm_zero_kernel(
    const float* __restrict__ A,
    const float* __restrict__ W,
    const float* __restrict__ bias,
    float* __restrict__ Hout,
    float* __restrict__ out)
{
    const int tid = threadIdx.x;

    if (blockIdx.x & 1) {
        // ---- zero role: stream 1.57 MB of zeros, nontemporal (don't thrash L2/L3) ----
        const int zid = blockIdx.x >> 1;
        f32x4* p = (f32x4*)out + (size_t)zid * ZF4_PER_BLOCK + tid;
        f32x4 z = (f32x4)0.0f;
#pragma unroll 8
        for (int i = 0; i < ZF4_ITERS; ++i) {
            __builtin_nontemporal_store(z, p);
            p += 256;
        }
        return;
    }

    // ---- GEMM role ----
    __shared__ float As[BK][LDSS];
    __shared__ float Bs[BK][LDSS];

    const int cid = blockIdx.x >> 1;        // 0..255
    const int n0 = (cid & 7) * BN;
    const int m0 = (cid >> 3) * BM;
    const int tx = tid & 15;                // column group
    const int ty = tid >> 4;                // row group

    // loader: each thread loads rows (lrow, lrow+64), 4 consecutive K, from A and W
    const int lrow = tid >> 2;              // 0..63
    const int lcol = (tid & 3) * 4;         // 0,4,8,12

    float acc[8][8];
#pragma unroll
    for (int i = 0; i < 8; ++i)
#pragma unroll
        for (int j = 0; j < 8; ++j) acc[i][j] = 0.f;

    const float* Aptr = A + (size_t)(m0 + lrow) * HID + lcol;
    const float* Bptr = W + (size_t)(n0 + lrow) * HID + lcol;

    // prefetch first K-tile
    float4 a0 = *(const float4*)(Aptr);
    float4 a1 = *(const float4*)(Aptr + (size_t)64 * HID);
    float4 b0 = *(const float4*)(Bptr);
    float4 b1 = *(const float4*)(Bptr + (size_t)64 * HID);

    for (int k0 = 0; k0 < HID / BK; ++k0) {
        __syncthreads();   // previous iter's LDS reads done
        As[lcol + 0][lrow] = a0.x; As[lcol + 1][lrow] = a0.y;
        As[lcol + 2][lrow] = a0.z; As[lcol + 3][lrow] = a0.w;
        As[lcol + 0][lrow + 64] = a1.x; As[lcol + 1][lrow + 64] = a1.y;
        As[lcol + 2][lrow + 64] = a1.z; As[lcol + 3][lrow + 64] = a1.w;
        Bs[lcol + 0][lrow] = b0.x; Bs[lcol + 1][lrow] = b0.y;
        Bs[lcol + 2][lrow] = b0.z; Bs[lcol + 3][lrow] = b0.w;
        Bs[lcol + 0][lrow + 64] = b1.x; Bs[lcol + 1][lrow + 64] = b1.y;
        Bs[lcol + 2][lrow + 64] = b1.z; Bs[lcol + 3][lrow + 64] = b1.w;
        __syncthreads();

        if (k0 + 1 < HID / BK) {
            // prefetch next K-tile; latency hides under the FMA section below
            const int kk = (k0 + 1) * BK;
            a0 = *(const float4*)(Aptr + kk);
            a1 = *(const float4*)(Aptr + kk + (size_t)64 * HID);
            b0 = *(const float4*)(Bptr + kk);
            b1 = *(const float4*)(Bptr + kk + (size_t)64 * HID);
        }

#pragma unroll
        for (int k = 0; k < BK; ++k) {
            // A fragment: rows ty*8..ty*8+7 (16-lane broadcast, conflict-free)
            f32x4 av0 = *(const f32x4*)&As[k][ty * 8];
            f32x4 av1 = *(const f32x4*)&As[k][ty * 8 + 4];
            // B fragment: cols tx*4 and 64+tx*4 (consecutive 16B chunks -> <=2-way, free)
            f32x4 bv0 = *(const f32x4*)&Bs[k][tx * 4];
            f32x4 bv1 = *(const f32x4*)&Bs[k][64 + tx * 4];
            float ar[8] = {av0.x, av0.y, av0.z, av0.w, av1.x, av1.y, av1.z, av1.w};
            float br[8] = {bv0.x, bv0.y, bv0.z, bv0.w, bv1.x, bv1.y, bv1.z, bv1.w};
#pragma unroll
            for (int i = 0; i < 8; ++i)
#pragma unroll
                for (int j = 0; j < 8; ++j)
                    acc[i][j] = fmaf(ar[i], br[j], acc[i][j]);
        }
    }

    float bc[8];
#pragma unroll
    for (int j = 0; j < 4; ++j) {
        bc[j]     = bias[n0 + tx * 4 + j];
        bc[j + 4] = bias[n0 + 64 + tx * 4 + j];
    }

#pragma unroll
    for (int i = 0; i < 8; ++i) {
        float o[8];
#pragma unroll
        for (int j = 0; j < 8; ++j) o[j] = fmaxf(acc[i][j] + bc[j], 0.f);
        float* dst = Hout + (size_t)(m0 + ty * 8 + i) * HID + n0;
        *(float4*)(dst + tx * 4)      = make_float4(o[0], o[1], o[2], o[3]);
        *(float4*)(dst + 64 + tx * 4) = make_float4(o[4], o[5], o[6], o[7]);
    }
}

// ---------------- Router: logits, softmax, top-2, scatter ----------------
// one wave (64 lanes) per token
__global__ __launch_bounds__(256) void router_kernel(
    const float* __restrict__ Hbuf,   // [4096,1024]
    const float* __restrict__ W2,     // [8,1024]
    const float* __restrict__ B2,     // [8]
    float* __restrict__ out)
{
    const int tid  = threadIdx.x;
    const int lane = tid & 63;
    const int wave = tid >> 6;
    const int t    = blockIdx.x * 4 + wave;
    if (t >= NTOK) return;

    const float* hrow = Hbuf + (size_t)t * HID;

    float p[NEXP];
#pragma unroll
    for (int e = 0; e < NEXP; ++e) p[e] = 0.f;

    for (int i = lane; i < HID; i += 64) {
        float x = hrow[i];
#pragma unroll
        for (int e = 0; e < NEXP; ++e)
            p[e] = fmaf(x, W2[e * HID + i], p[e]);
    }

#pragma unroll
    for (int e = 0; e < NEXP; ++e) {
        float v = p[e];
        v += __shfl_xor(v, 32, 64);
        v += __shfl_xor(v, 16, 64);
        v += __shfl_xor(v, 8, 64);
        v += __shfl_xor(v, 4, 64);
        v += __shfl_xor(v, 2, 64);
        v += __shfl_xor(v, 1, 64);
        p[e] = v + B2[e];
    }

    // softmax (all lanes redundantly)
    float mx = p[0];
#pragma unroll
    for (int e = 1; e < NEXP; ++e) mx = fmaxf(mx, p[e]);
    float pr[NEXP];
    float s = 0.f;
#pragma unroll
    for (int e = 0; e < NEXP; ++e) { pr[e] = expf(p[e] - mx); s += pr[e]; }
    float inv = 1.f / s;
#pragma unroll
    for (int e = 0; e < NEXP; ++e) pr[e] *= inv;

    // top-2, jax tie-break (lowest index wins on exact tie -> strict >)
    int e1 = 0; float p1 = pr[0];
#pragma unroll
    for (int e = 1; e < NEXP; ++e) { if (pr[e] > p1) { p1 = pr[e]; e1 = e; } }
    int e2 = -1; float p2 = -1.f;
#pragma unroll
    for (int e = 0; e < NEXP; ++e) { if (e != e1 && pr[e] > p2) { p2 = pr[e]; e2 = e; } }
    float invs = 1.f / (p1 + p2);

    if (lane < NEXP)
        out[RP_OFF + (size_t)t * NEXP + lane] = pr[lane];
    if (lane == 0) {
        size_t base = (size_t)t * NEXP;
        out[DISP_OFF + (base + e1) * CAP] = 1.0f;
        out[DISP_OFF + (base + e2) * CAP] = 1.0f;
        out[COMB_OFF + (base + e1) * CAP] = p1 * invs;
        out[COMB_OFF + (base + e2) * CAP] = p2 * invs;
    }
}

// ---------------- Aux loss ----------------
__global__ __launch_bounds__(256) void aux_kernel(float* __restrict__ out)
{
    __shared__ float sm[NEXP][257];
    const int tid = threadIdx.x;
    float s[NEXP];
#pragma unroll
    for (int e = 0; e < NEXP; ++e) s[e] = 0.f;

    const float* rp = out + RP_OFF;
    for (int t = tid; t < NTOK; t += 256) {
        float4 v0 = *(const float4*)&rp[(size_t)t * NEXP];
        float4 v1 = *(const float4*)&rp[(size_t)t * NEXP + 4];
        s[0] += v0.x; s[1] += v0.y; s[2] += v0.z; s[3] += v0.w;
        s[4] += v1.x; s[5] += v1.y; s[6] += v1.z; s[7] += v1.w;
    }
#pragma unroll
    for (int e = 0; e < NEXP; ++e) sm[e][tid] = s[e];
    __syncthreads();
    for (int st = 128; st > 0; st >>= 1) {
        if (tid < st) {
#pragma unroll
            for (int e = 0; e < NEXP; ++e) sm[e][tid] += sm[e][tid + st];
        }
        __syncthreads();
    }
    if (tid == 0) {
        float loss = 0.f;
#pragma unroll
        for (int e = 0; e < NEXP; ++e) {
            float m = sm[e][0] * (1.0f / NTOK);
            loss += m * logf(m * (float)NEXP + 1e-9f);
        }
        out[AUX_OFF] = loss;
    }
}

extern "C" void kernel_launch(void* const* d_in, const int* in_sizes, int n_in,
                              void* d_out, int out_size, void* d_ws, size_t ws_size,
                              hipStream_t stream)
{
    const float* x  = (const float*)d_in[0];   // [2,2048,1024]
    const float* w1 = (const float*)d_in[1];   // [1024,1024]
    const float* b1 = (const float*)d_in[2];   // [1024]
    const float* w2 = (const float*)d_in[3];   // [8,1024]
    const float* b2 = (const float*)d_in[4];   // [8]
    float* out  = (float*)d_out;
    float* hbuf = (float*)d_ws;                // needs 4096*1024*4 = 16.78 MB

    // 512 blocks: even = 256 GEMM tiles (32m x 8n), odd = 256 zero-fill slices.
    // Zero-fill (402.7 MB writes, HBM-bound) co-schedules with GEMM (VALU-bound):
    // total ~= max(gemm, memset) instead of sum.
    fused_gemm_zero_kernel<<<512, 256, 0, stream>>>(x, w1, b1, hbuf, out);
    router_kernel<<<NTOK / 4, 256, 0, stream>>>(hbuf, w2, b2, out);
    aux_kernel<<<1, 256, 0, stream>>>(out);
}

// Round 3
// 566.398 us; speedup vs baseline: 1.0537x; 1.0537x over previous
//
#include <hip/hip_runtime.h>
#include <math.h>

// Problem constants
#define HID   1024
#define NEXP  8
#define CAP   1536
#define NTOK  4096   // B*S = 2*2048

// Output layout (fp32 elements), concatenated flat in reference return order:
//   dispatch [4096,8,1536] | combine [4096,8,1536] | router_probs [4096,8] | aux [1]
#define DISP_OFF 0ull
#define COMB_OFF 50331648ull
#define RP_OFF   100663296ull
#define AUX_OFF  100696064ull

typedef float f32x4 __attribute__((ext_vector_type(4)));

// ---------------- Fused kernel ----------------
// even blocks: GEMM h=relu(x@w1^T+b1) tile 64x128, epilogue computes partial
//              logits for its 128-col slice -> part[nslice][token][expert]
// odd blocks:  zero-fill a 768 KB slice of dispatch+combine (nontemporal)
#define BM 64
#define BN 128
#define BK 16
#define LDA (BM + 4)    // 68 floats  (68%4==0 keeps float4 alignment)
#define LDB (BN + 4)    // 132 floats

// zero-fill: 2*50331648 floats = 25,165,824 float4 over 512 blocks = 49152/block
#define ZITER 192       // 49152 / 256 threads

__global__ __launch_bounds__(256) void fused_kernel(
    const float* __restrict__ A,      // x   [4096,1024]
    const float* __restrict__ W,      // w1  [1024,1024]  (row = output dim, K-contiguous)
    const float* __restrict__ bias,   // b1  [1024]
    const float* __restrict__ W2,     // w2  [8,1024]
    float* __restrict__ part,         // ws: [8][4096][8] partial logits
    float* __restrict__ out)
{
    const int tid = threadIdx.x;

    if (blockIdx.x & 1) {
        // ---- zero role ----
        const int zid = blockIdx.x >> 1;           // 0..511
        f32x4* p = (f32x4*)out + (size_t)zid * (ZITER * 256) + tid;
        f32x4 z = (f32x4)0.0f;
#pragma unroll 8
        for (int i = 0; i < ZITER; ++i) {
            __builtin_nontemporal_store(z, p);
            p += 256;
        }
        return;
    }

    // ---- GEMM role ----
    __shared__ float As[BK][LDA];
    __shared__ float Bs[BK][LDB];
    __shared__ float w2s[NEXP][BN];

    const int cid = blockIdx.x >> 1;   // 0..511
    const int ns  = cid & 7;           // n-slice 0..7
    const int n0  = ns * BN;
    const int m0  = (cid >> 3) * BM;   // 0..4032
    const int tx  = tid & 15;          // col group: cols tx*4..+3 and 64+tx*4..+3
    const int ty  = tid >> 4;          // row group: rows ty*4..+3
    const int lr  = tid >> 2;          // loader row 0..63
    const int lc  = (tid & 3) * 4;     // loader col 0,4,8,12

    // stage w2 slice for epilogue: w2s[e][c] = W2[e*HID + n0 + c]
    {
        const int e = tid >> 5;            // 0..7
        const int c = (tid & 31) * 4;      // 0..124
        *(f32x4*)&w2s[e][c] = *(const f32x4*)&W2[(size_t)e * HID + n0 + c];
    }

    float acc[4][8];
#pragma unroll
    for (int i = 0; i < 4; ++i)
#pragma unroll
        for (int j = 0; j < 8; ++j) acc[i][j] = 0.f;

    const float* Ap = A + (size_t)(m0 + lr) * HID + lc;
    const float* Bp = W + (size_t)(n0 + lr) * HID + lc;

    // prefetch first K-tile
    float4 a0 = *(const float4*)(Ap);
    float4 b0 = *(const float4*)(Bp);
    float4 b1 = *(const float4*)(Bp + (size_t)64 * HID);

    for (int k0 = 0; k0 < HID / BK; ++k0) {
        __syncthreads();   // previous iter's LDS reads done (also covers w2s stage)
        As[lc + 0][lr] = a0.x; As[lc + 1][lr] = a0.y;
        As[lc + 2][lr] = a0.z; As[lc + 3][lr] = a0.w;
        Bs[lc + 0][lr] = b0.x; Bs[lc + 1][lr] = b0.y;
        Bs[lc + 2][lr] = b0.z; Bs[lc + 3][lr] = b0.w;
        Bs[lc + 0][64 + lr] = b1.x; Bs[lc + 1][64 + lr] = b1.y;
        Bs[lc + 2][64 + lr] = b1.z; Bs[lc + 3][64 + lr] = b1.w;
        __syncthreads();

        if (k0 + 1 < HID / BK) {
            const int kk = (k0 + 1) * BK;   // prefetch next tile; hides under FMAs
            a0 = *(const float4*)(Ap + kk);
            b0 = *(const float4*)(Bp + kk);
            b1 = *(const float4*)(Bp + kk + (size_t)64 * HID);
        }

#pragma unroll
        for (int k = 0; k < BK; ++k) {
            // A frag: 16-lane broadcast (4 unique 16B addrs/wave) — conflict-free
            f32x4 av = *(const f32x4*)&As[k][ty * 4];
            // B frags: 16 consecutive 16B chunks, duplicated 4x — <=2-way (free)
            f32x4 bv0 = *(const f32x4*)&Bs[k][tx * 4];
            f32x4 bv1 = *(const f32x4*)&Bs[k][64 + tx * 4];
            float ar[4] = {av.x, av.y, av.z, av.w};
            float br[8] = {bv0.x, bv0.y, bv0.z, bv0.w, bv1.x, bv1.y, bv1.z, bv1.w};
#pragma unroll
            for (int i = 0; i < 4; ++i)
#pragma unroll
                for (int j = 0; j < 8; ++j)
                    acc[i][j] = fmaf(ar[i], br[j], acc[i][j]);
        }
    }

    // ---- epilogue: h = relu(acc + b1), then partial logits over this n-slice ----
    float bc[8];
#pragma unroll
    for (int j = 0; j < 4; ++j) {
        bc[j]     = bias[n0 + tx * 4 + j];
        bc[j + 4] = bias[n0 + 64 + tx * 4 + j];
    }
#pragma unroll
    for (int i = 0; i < 4; ++i)
#pragma unroll
        for (int j = 0; j < 8; ++j)
            acc[i][j] = fmaxf(acc[i][j] + bc[j], 0.f);

    // pl[i][e] = sum_j h[i][j] * w2s[e][col(j)]
    float pl[4][NEXP];
#pragma unroll
    for (int i = 0; i < 4; ++i)
#pragma unroll
        for (int e = 0; e < NEXP; ++e) {
            float s = 0.f;
#pragma unroll
            for (int j = 0; j < 4; ++j) s = fmaf(acc[i][j], w2s[e][tx * 4 + j], s);
#pragma unroll
            for (int j = 0; j < 4; ++j) s = fmaf(acc[i][j + 4], w2s[e][64 + tx * 4 + j], s);
            pl[i][e] = s;
        }

    // reduce across the 16 tx-lanes (contiguous within a wave) — deterministic tree
#pragma unroll
    for (int m = 1; m <= 8; m <<= 1)
#pragma unroll
        for (int i = 0; i < 4; ++i)
#pragma unroll
            for (int e = 0; e < NEXP; ++e)
                pl[i][e] += __shfl_xor(pl[i][e], m, 64);

    if (tx == 0) {
        // rows m0+ty*4 .. +3, 8 experts each: 32 consecutive floats
        float* dst = part + ((size_t)ns * NTOK + (m0 + ty * 4)) * NEXP;
#pragma unroll
        for (int i = 0; i < 4; ++i) {
            *(f32x4*)&dst[i * NEXP]     = *(f32x4*)&pl[i][0];
            *(f32x4*)&dst[i * NEXP + 4] = *(f32x4*)&pl[i][4];
        }
    }
}

// ---------------- Router: sum partials, softmax, top-2, scatter ----------------
// one thread per token
__global__ __launch_bounds__(256) void router2_kernel(
    const float* __restrict__ part,   // [8][4096][8]
    const float* __restrict__ B2,     // [8]
    float* __restrict__ out)
{
    const int t = blockIdx.x * 256 + threadIdx.x;

    float lg[NEXP];
#pragma unroll
    for (int e = 0; e < NEXP; ++e) lg[e] = B2[e];

#pragma unroll
    for (int s = 0; s < 8; ++s) {   // fixed slice order -> deterministic
        const float* p = part + ((size_t)s * NTOK + t) * NEXP;
        f32x4 v0 = *(const f32x4*)p;
        f32x4 v1 = *(const f32x4*)(p + 4);
        lg[0] += v0.x; lg[1] += v0.y; lg[2] += v0.z; lg[3] += v0.w;
        lg[4] += v1.x; lg[5] += v1.y; lg[6] += v1.z; lg[7] += v1.w;
    }

    float mx = lg[0];
#pragma unroll
    for (int e = 1; e < NEXP; ++e) mx = fmaxf(mx, lg[e]);
    float pr[NEXP], s = 0.f;
#pragma unroll
    for (int e = 0; e < NEXP; ++e) { pr[e] = expf(lg[e] - mx); s += pr[e]; }
    float inv = 1.f / s;
#pragma unroll
    for (int e = 0; e < NEXP; ++e) pr[e] *= inv;

    // top-2, lowest index wins ties (strict >)
    int e1 = 0; float p1 = pr[0];
#pragma unroll
    for (int e = 1; e < NEXP; ++e) { if (pr[e] > p1) { p1 = pr[e]; e1 = e; } }
    int e2 = -1; float p2 = -1.f;
#pragma unroll
    for (int e = 0; e < NEXP; ++e) { if (e != e1 && pr[e] > p2) { p2 = pr[e]; e2 = e; } }
    float invs = 1.f / (p1 + p2);

    float* rp = out + RP_OFF + (size_t)t * NEXP;
    *(f32x4*)rp       = *(f32x4*)&pr[0];
    *(f32x4*)(rp + 4) = *(f32x4*)&pr[4];

    const size_t base = (size_t)t * NEXP;
    out[DISP_OFF + (base + e1) * CAP] = 1.0f;
    out[DISP_OFF + (base + e2) * CAP] = 1.0f;
    out[COMB_OFF + (base + e1) * CAP] = p1 * invs;
    out[COMB_OFF + (base + e2) * CAP] = p2 * invs;
}

// ---------------- Aux loss ----------------
__global__ __launch_bounds__(256) void aux_kernel(float* __restrict__ out)
{
    __shared__ float sm[NEXP][257];
    const int tid = threadIdx.x;
    float s[NEXP];
#pragma unroll
    for (int e = 0; e < NEXP; ++e) s[e] = 0.f;

    const float* rp = out + RP_OFF;
    for (int t = tid; t < NTOK; t += 256) {
        f32x4 v0 = *(const f32x4*)&rp[(size_t)t * NEXP];
        f32x4 v1 = *(const f32x4*)&rp[(size_t)t * NEXP + 4];
        s[0] += v0.x; s[1] += v0.y; s[2] += v0.z; s[3] += v0.w;
        s[4] += v1.x; s[5] += v1.y; s[6] += v1.z; s[7] += v1.w;
    }
#pragma unroll
    for (int e = 0; e < NEXP; ++e) sm[e][tid] = s[e];
    __syncthreads();
    for (int st = 128; st > 0; st >>= 1) {
        if (tid < st) {
#pragma unroll
            for (int e = 0; e < NEXP; ++e) sm[e][tid] += sm[e][tid + st];
        }
        __syncthreads();
    }
    if (tid == 0) {
        float loss = 0.f;
#pragma unroll
        for (int e = 0; e < NEXP; ++e) {
            float m = sm[e][0] * (1.0f / NTOK);
            loss += m * logf(m * (float)NEXP + 1e-9f);
        }
        out[AUX_OFF] = loss;
    }
}

extern "C" void kernel_launch(void* const* d_in, const int* in_sizes, int n_in,
                              void* d_out, int out_size, void* d_ws, size_t ws_size,
                              hipStream_t stream)
{
    const float* x  = (const float*)d_in[0];   // [2,2048,1024]
    const float* w1 = (const float*)d_in[1];   // [1024,1024]
    const float* b1 = (const float*)d_in[2];   // [1024]
    const float* w2 = (const float*)d_in[3];   // [8,1024]
    const float* b2 = (const float*)d_in[4];   // [8]
    float* out  = (float*)d_out;
    float* part = (float*)d_ws;                // [8][4096][8] = 1 MB

    // 1024 blocks: even = 512 GEMM tiles (64m x 128n, full K) with fused
    // layer-2 partial-logit epilogue; odd = 512 zero-fill slices (402.7 MB).
    // Every part[] element is written by exactly one block -> no init needed.
    fused_kernel<<<1024, 256, 0, stream>>>(x, w1, b1, w2, part, out);
    router2_kernel<<<NTOK / 256, 256, 0, stream>>>(part, b2, out);
    aux_kernel<<<1, 256, 0, stream>>>(out);
}